// Round 5
// baseline (535.832 us; speedup 1.0000x reference)
//
#include <hip/hip_runtime.h>
#include <math.h>

// Problem constants
#define BATCH 64
#define LDIM  256
#define HDIM  1024
#define DDIM  1024
#define BAND  16
#define MNZ   33          // 2*BAND+1
#define NN    (DDIM*MNZ)  // 33792
#define RTILE 64          // k3 rows per block
#define LSTR  34          // LDS row stride (pad 33->34)
#define NSPLIT 8
#define KCHUNK (HDIM / NSPLIT)   // 128

typedef float v4f __attribute__((ext_vector_type(4)));

// ---------------------------------------------------------------------------
// K1: h = gelu(z @ W1 + b1), written TRANSPOSED: ht[k][b]  (k-major)
// ---------------------------------------------------------------------------
__global__ __launch_bounds__(256) void k1_h(const float* __restrict__ z,
                                            const float* __restrict__ W1,
                                            const float* __restrict__ b1,
                                            float* __restrict__ ht) {
    __shared__ float zs[LDIM];
    const int t = threadIdx.x;
    const int b = blockIdx.y;
    const int j = blockIdx.x * 256 + t;
    zs[t] = z[b * LDIM + t];
    __syncthreads();
    float acc = b1[j];
#pragma unroll 8
    for (int l = 0; l < LDIM; ++l)
        acc = fmaf(zs[l], W1[l * HDIM + j], acc);
    float g = 0.5f * acc * (1.0f + erff(acc * 0.70710678118654752f));
    ht[(size_t)j * BATCH + b] = g;
}

// ---------------------------------------------------------------------------
// K2: v = h @ W2 (+ b2 on slice 0), K split NSPLIT ways into partials.
// Grid (132, NSPLIT) = 1056 blocks (~4/CU). Block: 256 cols x all 64 batches.
// h chunk (KCHUNK x 64 = 32 KB) staged once in LDS; inner loop = 1 prefetched
// W2 v4f stream load + 4 broadcast LDS v4f reads + 64 fma.
// ---------------------------------------------------------------------------
__global__ __launch_bounds__(256) void k2_v(const float* __restrict__ W2,
                                            const float* __restrict__ b2,
                                            const float* __restrict__ ht,
                                            float* __restrict__ vpart) {
    __shared__ float lsh[KCHUNK * BATCH];   // 32 KB
    const int tid  = threadIdx.x;
    const int lane = tid & 63;
    const int wave = __builtin_amdgcn_readfirstlane(tid >> 6);
    const int c0 = blockIdx.x * 256 + lane * 4;
    const int b0 = wave * 16;
    const int ks = blockIdx.y * KCHUNK;

    // stage h[ks..ks+KCHUNK) x 64 batches (contiguous 32 KB, coalesced)
    {
        const v4f* __restrict__ src = (const v4f*)(ht + (size_t)ks * BATCH);
        v4f* dst = (v4f*)lsh;
#pragma unroll
        for (int i = 0; i < (KCHUNK * BATCH) / (4 * 256); ++i)
            dst[tid + i * 256] = src[tid + i * 256];
    }
    __syncthreads();

    v4f acc[16];
#pragma unroll
    for (int j = 0; j < 16; ++j) acc[j] = (v4f){0.f, 0.f, 0.f, 0.f};

    const float* __restrict__ wp = W2 + (size_t)ks * NN + c0;
    v4f wnext = *(const v4f*)wp;
    for (int kk = 0; kk < KCHUNK; ++kk) {
        const v4f w4 = wnext;
        const int knext = (kk + 1 < KCHUNK) ? (kk + 1) : (KCHUNK - 1);
        wnext = *(const v4f*)(wp + (size_t)knext * NN);
        const v4f* __restrict__ hh = (const v4f*)(lsh + kk * BATCH + b0);
        const v4f h0 = hh[0], h1 = hh[1], h2 = hh[2], h3 = hh[3];
        acc[0]  += h0.x * w4;  acc[1]  += h0.y * w4;
        acc[2]  += h0.z * w4;  acc[3]  += h0.w * w4;
        acc[4]  += h1.x * w4;  acc[5]  += h1.y * w4;
        acc[6]  += h1.z * w4;  acc[7]  += h1.w * w4;
        acc[8]  += h2.x * w4;  acc[9]  += h2.y * w4;
        acc[10] += h2.z * w4;  acc[11] += h2.w * w4;
        acc[12] += h3.x * w4;  acc[13] += h3.y * w4;
        acc[14] += h3.z * w4;  acc[15] += h3.w * w4;
    }

    float* __restrict__ vo = vpart + (size_t)blockIdx.y * (BATCH * (size_t)NN)
                             + (size_t)b0 * NN + c0;
    if (blockIdx.y == 0) {
        const v4f bias = *(const v4f*)(b2 + c0);
#pragma unroll
        for (int j = 0; j < 16; ++j)
            *(v4f*)(vo + (size_t)j * NN) = acc[j] + bias;
    } else {
#pragma unroll
        for (int j = 0; j < 16; ++j)
            *(v4f*)(vo + (size_t)j * NN) = acc[j];
    }
}

// ---------------------------------------------------------------------------
// K3: block = (batch b, 64-row tile). Stage v rows [i0-16, i0+80) into LDS
// (coalesced, summing NSPLIT slices), then 64 output rows of float4 NT stores.
// ---------------------------------------------------------------------------
__global__ __launch_bounds__(256) void k3_out(const float* __restrict__ vpart,
                                              float* __restrict__ out) {
    const int tid  = threadIdx.x;
    const int tile = blockIdx.x & (DDIM / RTILE - 1);
    const int b    = blockIdx.x / (DDIM / RTILE);
    const int i0 = tile * RTILE;
    const int js = (i0 >= BAND) ? (i0 - BAND) : 0;
    const int je = (i0 + RTILE + BAND <= DDIM) ? (i0 + RTILE + BAND) : DDIM;
    const int nelem = (je - js) * MNZ;                   // <= 3168

    __shared__ float ls[(RTILE + 2 * BAND) * LSTR];      // 12.75 KB

    const float* __restrict__ vb = vpart + (size_t)b * NN + (size_t)js * MNZ;
    const size_t slice = (size_t)BATCH * NN;
    for (int idx = tid; idx < nelem; idx += 256) {
        const int r = idx / MNZ;
        const int m = idx - r * MNZ;
        float s = 0.0f;
#pragma unroll
        for (int sl = 0; sl < NSPLIT; ++sl)
            s += vb[(size_t)sl * slice + idx];
        ls[r * LSTR + m] = s;
    }
    __syncthreads();

    const int j0 = tid * 4;
    for (int r = 0; r < RTILE; ++r) {
        const int i = i0 + r;
        v4f res = (v4f){0.f, 0.f, 0.f, 0.f};
        if (j0 + 3 >= i - BAND && j0 <= i + BAND) {
            const int lo_i = (i > BAND) ? (i - BAND) : 0;
#pragma unroll
            for (int c = 0; c < 4; ++c) {
                const int j = j0 + c;
                const int d = j - i;
                float x = 0.0f;
                if (d >= -BAND && d <= BAND) {
                    const int lo_j = (j > BAND) ? (j - BAND) : 0;
                    x = 0.5f * (ls[(i - js) * LSTR + (j - lo_i)] +
                                ls[(j - js) * LSTR + (i - lo_j)]);
                    if (d == 0) x += 1.0f;
                }
                res[c] = x;
            }
        }
        v4f* dst = ((v4f*)out) + ((size_t)b * DDIM + i) * (DDIM / 4) + tid;
        __builtin_nontemporal_store(res, dst);
    }
}

// ---------------------------------------------------------------------------
extern "C" void kernel_launch(void* const* d_in, const int* in_sizes, int n_in,
                              void* d_out, int out_size, void* d_ws, size_t ws_size,
                              hipStream_t stream) {
    const float* z  = (const float*)d_in[0];
    const float* W1 = (const float*)d_in[2];
    const float* b1 = (const float*)d_in[3];
    const float* W2 = (const float*)d_in[4];
    const float* b2 = (const float*)d_in[5];

    float* ht = (float*)d_ws;                 // 64*1024 floats
    float* vpart = ht + BATCH * HDIM;         // NSPLIT * 64*33792 floats (69 MB)
    float* out = (float*)d_out;

    k1_h  <<<dim3(4, 64), 256, 0, stream>>>(z, W1, b1, ht);
    k2_v  <<<dim3(NN / 256, NSPLIT), 256, 0, stream>>>(W2, b2, ht, vpart);
    k3_out<<<dim3(BATCH * (DDIM / RTILE)), 256, 0, stream>>>(vpart, out);
}

// Round 6
// 436.118 us; speedup vs baseline: 1.2286x; 1.2286x over previous
//
#include <hip/hip_runtime.h>
#include <hip/hip_bf16.h>
#include <math.h>

// Problem constants
#define BATCH 64
#define LDIM  256
#define HDIM  1024
#define DDIM  1024
#define BAND  16
#define MNZ   33          // 2*BAND+1
#define NN    (DDIM*MNZ)  // 33792
#define RTILE 64          // k3 rows per block
#define LSTR  34          // k3 LDS row stride (pad 33->34)
#define NSPLIT 4          // k2: waves per block = in-block K-split -> global partials
#define KW    (HDIM/NSPLIT)   // 256 K per wave
#define KSTEP 32              // one mfma_16x16x32 per step
#define NSTEPS (KW/KSTEP)     // 8
#define BROW  40              // k2 LDS B-tile row stride in bf16 units (32 + 8 pad)

typedef float  v4f    __attribute__((ext_vector_type(4)));
typedef float  f32x4  __attribute__((ext_vector_type(4)));
typedef short  bf16x8 __attribute__((ext_vector_type(8)));
typedef unsigned short u16x8 __attribute__((ext_vector_type(8)));

static __device__ __forceinline__ unsigned short f2bf(float x) {
    // round-to-nearest-even bf16
    union { float f; unsigned int u; } a; a.f = x;
    unsigned int r = a.u + 0x7fffu + ((a.u >> 16) & 1u);
    return (unsigned short)(r >> 16);
}

// ---------------------------------------------------------------------------
// K1: h = gelu(z @ W1 + b1) -> bf16, row-major hb[b][k] (A-fragment friendly)
// ---------------------------------------------------------------------------
__global__ __launch_bounds__(256) void k1_h(const float* __restrict__ z,
                                            const float* __restrict__ W1,
                                            const float* __restrict__ b1,
                                            unsigned short* __restrict__ hb) {
    __shared__ float zs[LDIM];
    const int t = threadIdx.x;
    const int b = blockIdx.y;
    const int j = blockIdx.x * 256 + t;
    zs[t] = z[b * LDIM + t];
    __syncthreads();
    float acc = b1[j];
#pragma unroll 8
    for (int l = 0; l < LDIM; ++l)
        acc = fmaf(zs[l], W1[l * HDIM + j], acc);
    float g = 0.5f * acc * (1.0f + erff(acc * 0.70710678118654752f));
    hb[(size_t)b * HDIM + j] = f2bf(g);
}

// ---------------------------------------------------------------------------
// K2: v = h @ W2 (+ b2 on slice 0) via bf16 MFMA 16x16x32.
// 528 blocks x 4 waves. Block = 64 cols; wave w = K-chunk [w*256, w*256+256),
// writes partial slice w (vpart[w]). Barrier-free: per-wave LDS B-tile.
// Per 32-k step/wave: 8 indep coalesced W2 dwordx4 loads -> bf16 pack ->
// LDS [n][k] -> 4 ds_read_b128 B-frags + 4 global A-frags -> 16 MFMAs.
// ---------------------------------------------------------------------------
__global__ __launch_bounds__(256) void k2_v(const float* __restrict__ W2,
                                            const float* __restrict__ b2,
                                            const unsigned short* __restrict__ hb,
                                            float* __restrict__ vpart) {
    __shared__ __align__(16) unsigned short Bt[4][64 * BROW];  // 4 x 5 KB
    const int tid  = threadIdx.x;
    const int lane = tid & 63;
    const int wave = __builtin_amdgcn_readfirstlane(tid >> 6);
    const int c0   = blockIdx.x * 64;
    const int k0   = wave * KW;
    const int kq   = lane >> 4;          // quad 0..3
    const int nl   = lane & 15;
    const int nq   = nl * 4;

    unsigned short* bt = &Bt[wave][0];

    f32x4 acc[4][4];
#pragma unroll
    for (int mt = 0; mt < 4; ++mt)
#pragma unroll
        for (int nt = 0; nt < 4; ++nt)
            acc[mt][nt] = (f32x4){0.f, 0.f, 0.f, 0.f};

#pragma unroll
    for (int s = 0; s < NSTEPS; ++s) {
        const int kb = k0 + s * KSTEP;
        // 8 independent W2 loads: lane covers k = kb+kq*8+j, n = c0+nq..+3
        v4f wld[8];
        const float* wp = W2 + (size_t)(kb + kq * 8) * NN + (c0 + nq);
#pragma unroll
        for (int j = 0; j < 8; ++j)
            wld[j] = *(const v4f*)(wp + (size_t)j * NN);
        // in-register transpose + bf16 pack: per owned n-col, 8 consecutive k
#pragma unroll
        for (int c = 0; c < 4; ++c) {
            u16x8 pk;
#pragma unroll
            for (int j = 0; j < 8; ++j) pk[j] = f2bf(wld[j][c]);
            *(u16x8*)(bt + (nq + c) * BROW + kq * 8) = pk;   // ds_write_b128
        }
        // A frags (global, L2-resident 128 KB): A[m=nl+16mt][k=kb+kq*8+j]
        bf16x8 af[4];
#pragma unroll
        for (int mt = 0; mt < 4; ++mt)
            af[mt] = *(const bf16x8*)(hb + (size_t)(mt * 16 + nl) * HDIM + kb + kq * 8);
        // B frags (LDS): B[k=kb+kq*8+j][n=nl+16nt]
        bf16x8 bfr[4];
#pragma unroll
        for (int nt = 0; nt < 4; ++nt)
            bfr[nt] = *(const bf16x8*)(bt + (nt * 16 + nl) * BROW + kq * 8);
#pragma unroll
        for (int mt = 0; mt < 4; ++mt)
#pragma unroll
            for (int nt = 0; nt < 4; ++nt)
                acc[mt][nt] = __builtin_amdgcn_mfma_f32_16x16x32_bf16(
                    af[mt], bfr[nt], acc[mt][nt], 0, 0, 0);
    }

    // epilogue: C[m= mt*16 + kq*4 + r][n= c0 + nt*16 + nl]
    float* __restrict__ vo = vpart + (size_t)wave * ((size_t)BATCH * NN);
#pragma unroll
    for (int nt = 0; nt < 4; ++nt) {
        const int col = c0 + nt * 16 + nl;
        const float bias = (wave == 0) ? b2[col] : 0.0f;
#pragma unroll
        for (int mt = 0; mt < 4; ++mt)
#pragma unroll
            for (int r = 0; r < 4; ++r)
                vo[(size_t)(mt * 16 + kq * 4 + r) * NN + col] = acc[mt][nt][r] + bias;
    }
}

// ---------------------------------------------------------------------------
// K3: block = (batch b, 64-row tile). Stage v rows [i0-16, i0+80) into LDS
// (coalesced, summing NSPLIT slices), then 64 output rows of float4 NT stores.
// ---------------------------------------------------------------------------
__global__ __launch_bounds__(256) void k3_out(const float* __restrict__ vpart,
                                              float* __restrict__ out) {
    const int tid  = threadIdx.x;
    const int tile = blockIdx.x & (DDIM / RTILE - 1);
    const int b    = blockIdx.x / (DDIM / RTILE);
    const int i0 = tile * RTILE;
    const int js = (i0 >= BAND) ? (i0 - BAND) : 0;
    const int je = (i0 + RTILE + BAND <= DDIM) ? (i0 + RTILE + BAND) : DDIM;
    const int nelem = (je - js) * MNZ;                   // <= 3168

    __shared__ float ls[(RTILE + 2 * BAND) * LSTR];      // 12.75 KB

    const float* __restrict__ vb = vpart + (size_t)b * NN + (size_t)js * MNZ;
    const size_t slice = (size_t)BATCH * NN;
    for (int idx = tid; idx < nelem; idx += 256) {
        const int r = idx / MNZ;
        const int m = idx - r * MNZ;
        float s = 0.0f;
#pragma unroll
        for (int sl = 0; sl < NSPLIT; ++sl)
            s += vb[(size_t)sl * slice + idx];
        ls[r * LSTR + m] = s;
    }
    __syncthreads();

    const int j0 = tid * 4;
    for (int r = 0; r < RTILE; ++r) {
        const int i = i0 + r;
        v4f res = (v4f){0.f, 0.f, 0.f, 0.f};
        if (j0 + 3 >= i - BAND && j0 <= i + BAND) {
            const int lo_i = (i > BAND) ? (i - BAND) : 0;
#pragma unroll
            for (int c = 0; c < 4; ++c) {
                const int j = j0 + c;
                const int d = j - i;
                float x = 0.0f;
                if (d >= -BAND && d <= BAND) {
                    const int lo_j = (j > BAND) ? (j - BAND) : 0;
                    x = 0.5f * (ls[(i - js) * LSTR + (j - lo_i)] +
                                ls[(j - js) * LSTR + (i - lo_j)]);
                    if (d == 0) x += 1.0f;
                }
                res[c] = x;
            }
        }
        v4f* dst = ((v4f*)out) + ((size_t)b * DDIM + i) * (DDIM / 4) + tid;
        __builtin_nontemporal_store(res, dst);
    }
}

// ---------------------------------------------------------------------------
extern "C" void kernel_launch(void* const* d_in, const int* in_sizes, int n_in,
                              void* d_out, int out_size, void* d_ws, size_t ws_size,
                              hipStream_t stream) {
    const float* z  = (const float*)d_in[0];
    const float* W1 = (const float*)d_in[2];
    const float* b1 = (const float*)d_in[3];
    const float* W2 = (const float*)d_in[4];
    const float* b2 = (const float*)d_in[5];

    unsigned short* hb = (unsigned short*)d_ws;          // 64x1024 bf16 (128 KB)
    float* vpart = (float*)((char*)d_ws + (size_t)BATCH * HDIM * sizeof(unsigned short));
    float* out = (float*)d_out;

    k1_h  <<<dim3(4, 64), 256, 0, stream>>>(z, W1, b1, hb);
    k2_v  <<<dim3(NN / 64), 256, 0, stream>>>(W2, b2, hb, vpart);
    k3_out<<<dim3(BATCH * (DDIM / RTILE)), 256, 0, stream>>>(vpart, out);
}

// Round 7
// 429.013 us; speedup vs baseline: 1.2490x; 1.0166x over previous
//
#include <hip/hip_runtime.h>
#include <hip/hip_bf16.h>
#include <math.h>

// Problem constants
#define BATCH 64
#define LDIM  256
#define HDIM  1024
#define DDIM  1024
#define BAND  16
#define MNZ   33          // 2*BAND+1
#define NN    (DDIM*MNZ)  // 33792
#define RTILE 64          // k3 rows per block
#define LSTR  34          // k3 LDS row stride (pad 33->34)
#define NSPLIT 4          // k2: waves per block = in-block K-split -> global partials
#define KW    (HDIM/NSPLIT)   // 256 K per wave
#define KSTEP 32              // one mfma_16x16x32 per step
#define NSTEPS (KW/KSTEP)     // 8 (must be even)
#define BROW  40              // k2 LDS B-tile row stride in bf16 units

typedef float  v4f    __attribute__((ext_vector_type(4)));
typedef float  f32x4  __attribute__((ext_vector_type(4)));
typedef short  bf16x8 __attribute__((ext_vector_type(8)));
typedef unsigned short u16x8 __attribute__((ext_vector_type(8)));

static __device__ __forceinline__ unsigned short f2bf(float x) {
    union { float f; unsigned int u; } a; a.f = x;
    unsigned int r = a.u + 0x7fffu + ((a.u >> 16) & 1u);
    return (unsigned short)(r >> 16);
}

// ---------------------------------------------------------------------------
// K1: h = gelu(z @ W1 + b1) -> bf16, row-major hb[b][k]
// ---------------------------------------------------------------------------
__global__ __launch_bounds__(256) void k1_h(const float* __restrict__ z,
                                            const float* __restrict__ W1,
                                            const float* __restrict__ b1,
                                            unsigned short* __restrict__ hb) {
    __shared__ float zs[LDIM];
    const int t = threadIdx.x;
    const int b = blockIdx.y;
    const int j = blockIdx.x * 256 + t;
    zs[t] = z[b * LDIM + t];
    __syncthreads();
    float acc = b1[j];
#pragma unroll 8
    for (int l = 0; l < LDIM; ++l)
        acc = fmaf(zs[l], W1[l * HDIM + j], acc);
    float g = 0.5f * acc * (1.0f + erff(acc * 0.70710678118654752f));
    hb[(size_t)b * HDIM + j] = f2bf(g);
}

// ---------------------------------------------------------------------------
// K2: v = h @ W2 (+ b2 on slice 0) via bf16 MFMA 16x16x32.
// 528 blocks x 4 waves. Block = 64 cols; wave w = K-chunk [w*256, ...),
// writes partial slice w. Barrier-free per-wave LDS B-tile.
// Step loop is unroll(1) with a hand-rolled depth-2 W2-load pipeline so the
// compiler CANNOT hoist all 64 loads (R6 suspect: VGPR blowup -> spills).
// ---------------------------------------------------------------------------
__global__ __launch_bounds__(256) void k2_v(const float* __restrict__ W2,
                                            const float* __restrict__ b2,
                                            const unsigned short* __restrict__ hb,
                                            float* __restrict__ vpart) {
    __shared__ __align__(16) unsigned short Bt[4][64 * BROW];  // 4 x 5 KB
    const int tid  = threadIdx.x;
    const int lane = tid & 63;
    const int wave = __builtin_amdgcn_readfirstlane(tid >> 6);
    const int c0   = blockIdx.x * 64;
    const int k0   = wave * KW;
    const int kq   = lane >> 4;          // quad 0..3
    const int nl   = lane & 15;
    const int nq   = nl * 4;

    unsigned short* bt = &Bt[wave][0];

    f32x4 acc[4][4];
#pragma unroll
    for (int mt = 0; mt < 4; ++mt)
#pragma unroll
        for (int nt = 0; nt < 4; ++nt)
            acc[mt][nt] = (f32x4){0.f, 0.f, 0.f, 0.f};

    const float* __restrict__ wp = W2 + (size_t)(k0 + kq * 8) * NN + (c0 + nq);
    const size_t stepoff = (size_t)KSTEP * NN;

    // consume one 32-K step: pack wld -> per-wave LDS, read frags, 16 MFMAs
    auto consume = [&](int s, v4f (&wld)[8]) {
        const int kb = k0 + s * KSTEP;
#pragma unroll
        for (int c = 0; c < 4; ++c) {
            u16x8 pk;
#pragma unroll
            for (int j = 0; j < 8; ++j) pk[j] = f2bf(wld[j][c]);
            *(u16x8*)(bt + (nq + c) * BROW + kq * 8) = pk;   // ds_write_b128
        }
        bf16x8 af[4];
#pragma unroll
        for (int mt = 0; mt < 4; ++mt)
            af[mt] = *(const bf16x8*)(hb + (size_t)(mt * 16 + nl) * HDIM + kb + kq * 8);
        bf16x8 bfr[4];
#pragma unroll
        for (int nt = 0; nt < 4; ++nt)
            bfr[nt] = *(const bf16x8*)(bt + (nt * 16 + nl) * BROW + kq * 8);
#pragma unroll
        for (int mt = 0; mt < 4; ++mt)
#pragma unroll
            for (int nt = 0; nt < 4; ++nt)
                acc[mt][nt] = __builtin_amdgcn_mfma_f32_16x16x32_bf16(
                    af[mt], bfr[nt], acc[mt][nt], 0, 0, 0);
    };

    v4f wldA[8], wldB[8];
#pragma unroll
    for (int j = 0; j < 8; ++j) wldA[j] = *(const v4f*)(wp + (size_t)j * NN);

#pragma unroll 1
    for (int sp = 0; sp < NSTEPS; sp += 2) {
        // prefetch step sp+1
        {
            const float* pb = wp + (size_t)(sp + 1) * stepoff;
#pragma unroll
            for (int j = 0; j < 8; ++j) wldB[j] = *(const v4f*)(pb + (size_t)j * NN);
        }
        consume(sp, wldA);
        // prefetch step sp+2 (clamped: last pair redundantly reloads a valid step)
        {
            const int sA = (sp + 2 < NSTEPS) ? (sp + 2) : (NSTEPS - 1);
            const float* pa = wp + (size_t)sA * stepoff;
#pragma unroll
            for (int j = 0; j < 8; ++j) wldA[j] = *(const v4f*)(pa + (size_t)j * NN);
        }
        consume(sp + 1, wldB);
    }

    // epilogue: C[m = mt*16 + kq*4 + r][n = c0 + nt*16 + nl]
    float* __restrict__ vo = vpart + (size_t)wave * ((size_t)BATCH * NN);
#pragma unroll
    for (int nt = 0; nt < 4; ++nt) {
        const int col = c0 + nt * 16 + nl;
        const float bias = (wave == 0) ? b2[col] : 0.0f;
#pragma unroll
        for (int mt = 0; mt < 4; ++mt)
#pragma unroll
            for (int r = 0; r < 4; ++r)
                vo[(size_t)(mt * 16 + kq * 4 + r) * NN + col] = acc[mt][nt][r] + bias;
    }
}

// ---------------------------------------------------------------------------
// K3: block = (batch b, 64-row tile). Stage v rows [i0-16, i0+80) into LDS
// (coalesced, summing NSPLIT slices), then 64 output rows of float4 NT stores.
// ---------------------------------------------------------------------------
__global__ __launch_bounds__(256) void k3_out(const float* __restrict__ vpart,
                                              float* __restrict__ out) {
    const int tid  = threadIdx.x;
    const int tile = blockIdx.x & (DDIM / RTILE - 1);
    const int b    = blockIdx.x / (DDIM / RTILE);
    const int i0 = tile * RTILE;
    const int js = (i0 >= BAND) ? (i0 - BAND) : 0;
    const int je = (i0 + RTILE + BAND <= DDIM) ? (i0 + RTILE + BAND) : DDIM;
    const int nelem = (je - js) * MNZ;                   // <= 3168

    __shared__ float ls[(RTILE + 2 * BAND) * LSTR];      // 12.75 KB

    const float* __restrict__ vb = vpart + (size_t)b * NN + (size_t)js * MNZ;
    const size_t slice = (size_t)BATCH * NN;
    for (int idx = tid; idx < nelem; idx += 256) {
        const int r = idx / MNZ;
        const int m = idx - r * MNZ;
        float s = 0.0f;
#pragma unroll
        for (int sl = 0; sl < NSPLIT; ++sl)
            s += vb[(size_t)sl * slice + idx];
        ls[r * LSTR + m] = s;
    }
    __syncthreads();

    const int j0 = tid * 4;
#pragma unroll 2
    for (int r = 0; r < RTILE; ++r) {
        const int i = i0 + r;
        v4f res = (v4f){0.f, 0.f, 0.f, 0.f};
        if (j0 + 3 >= i - BAND && j0 <= i + BAND) {
            const int lo_i = (i > BAND) ? (i - BAND) : 0;
#pragma unroll
            for (int c = 0; c < 4; ++c) {
                const int j = j0 + c;
                const int d = j - i;
                float x = 0.0f;
                if (d >= -BAND && d <= BAND) {
                    const int lo_j = (j > BAND) ? (j - BAND) : 0;
                    x = 0.5f * (ls[(i - js) * LSTR + (j - lo_i)] +
                                ls[(j - js) * LSTR + (i - lo_j)]);
                    if (d == 0) x += 1.0f;
                }
                res[c] = x;
            }
        }
        v4f* dst = ((v4f*)out) + ((size_t)b * DDIM + i) * (DDIM / 4) + tid;
        __builtin_nontemporal_store(res, dst);
    }
}

// ---------------------------------------------------------------------------
extern "C" void kernel_launch(void* const* d_in, const int* in_sizes, int n_in,
                              void* d_out, int out_size, void* d_ws, size_t ws_size,
                              hipStream_t stream) {
    const float* z  = (const float*)d_in[0];
    const float* W1 = (const float*)d_in[2];
    const float* b1 = (const float*)d_in[3];
    const float* W2 = (const float*)d_in[4];
    const float* b2 = (const float*)d_in[5];

    unsigned short* hb = (unsigned short*)d_ws;          // 64x1024 bf16 (128 KB)
    float* vpart = (float*)((char*)d_ws + (size_t)BATCH * HDIM * sizeof(unsigned short));
    float* out = (float*)d_out;

    k1_h  <<<dim3(4, 64), 256, 0, stream>>>(z, W1, b1, hb);
    k2_v  <<<dim3(NN / 64), 256, 0, stream>>>(W2, b2, hb, vpart);
    k3_out<<<dim3(BATCH * (DDIM / RTILE)), 256, 0, stream>>>(vpart, out);
}